// Round 5
// baseline (493.533 us; speedup 1.0000x reference)
//
#include <hip/hip_runtime.h>

typedef __bf16 bf16;
typedef __attribute__((ext_vector_type(8))) __bf16 bf16x8;
typedef __attribute__((ext_vector_type(4))) float floatx4;

#define TOK 2048
#define DD  1024
#define NE  8
#define MAXSLOT 72   // max worklist entries: <=40 routed (BM=64) + 32 shared

#define MFMA16(A,B,C) __builtin_amdgcn_mfma_f32_16x16x32_bf16(A,B,C,0,0,0)

__device__ __forceinline__ bf16x8 pack_bf8v(float4 a, float4 b) {
  union { bf16 h[8]; bf16x8 v; } p;
  p.h[0] = (bf16)a.x; p.h[1] = (bf16)a.y; p.h[2] = (bf16)a.z; p.h[3] = (bf16)a.w;
  p.h[4] = (bf16)b.x; p.h[5] = (bf16)b.y; p.h[6] = (bf16)b.z; p.h[7] = (bf16)b.w;
  return p.v;
}

// ---------------- gate + x->bf16 + ss zero-init ----------------
__global__ __launch_bounds__(256) void gate_cvt_kernel(
    const float* __restrict__ x, const float* __restrict__ gate_w,
    const float* __restrict__ gate_b, bf16* __restrict__ x_bf,
    int* __restrict__ eidx, float* __restrict__ ewgt, float* __restrict__ ss)
{
  const int t = blockIdx.x, tid = threadIdx.x;
  if (tid < 4) ss[tid * TOK + t] = 0.f;   // zero ss_r/ss_z/ss_or/ss_oz for this token
  const float4 v = ((const float4*)(x + (size_t)t * DD))[tid];
  union { bf16 h[4]; uint2 u; } pk;
  pk.h[0] = (bf16)v.x; pk.h[1] = (bf16)v.y; pk.h[2] = (bf16)v.z; pk.h[3] = (bf16)v.w;
  ((uint2*)(x_bf + (size_t)t * DD))[tid] = pk.u;

  float acc[NE];
#pragma unroll
  for (int e = 0; e < NE; ++e) acc[e] = 0.f;
  const float vv[4] = {v.x, v.y, v.z, v.w};
#pragma unroll
  for (int i = 0; i < 4; ++i) {
    const int d = tid * 4 + i;
    if (d >= 1) {
#pragma unroll
      for (int e = 0; e < NE; ++e) acc[e] += vv[i] * gate_w[e * (DD - 1) + d - 1];
    }
  }
#pragma unroll
  for (int off = 32; off > 0; off >>= 1) {
#pragma unroll
    for (int e = 0; e < NE; ++e) acc[e] += __shfl_down(acc[e], off);
  }
  __shared__ float red[4][NE];
  const int wid = tid >> 6, lane = tid & 63;
  if (lane == 0) {
#pragma unroll
    for (int e = 0; e < NE; ++e) red[wid][e] = acc[e];
  }
  __syncthreads();
  if (tid == 0) {
    float lg[NE];
#pragma unroll
    for (int e = 0; e < NE; ++e) lg[e] = red[0][e] + red[1][e] + red[2][e] + red[3][e];
    float m = lg[0];
    for (int e = 1; e < NE; ++e) m = fmaxf(m, lg[e]);
    float ex[NE], s = 0.f;
    for (int e = 0; e < NE; ++e) { ex[e] = expf(lg[e] - m); s += ex[e]; }
    const float inv = 1.f / s;
    int best = 0; float bb = ex[0] * inv + gate_b[0];
    for (int e = 1; e < NE; ++e) {
      const float b = ex[e] * inv + gate_b[e];
      if (b > bb) { bb = b; best = e; }
    }
    eidx[t] = best;
    ewgt[t] = ex[best] * inv;
  }
}

// ---------------- routing: count + prefix + scatter + WORKLIST ----------------
__global__ __launch_bounds__(256) void route_kernel(
    const int* __restrict__ eidx, int* __restrict__ perm,
    int* __restrict__ pos_of, int4* __restrict__ wl, int* __restrict__ wl_n)
{
  __shared__ int cnt[NE], off[NE], bas[NE + 1];
  const int tid = threadIdx.x;
  if (tid < NE) cnt[tid] = 0;
  __syncthreads();
  for (int t = tid; t < TOK; t += 256) atomicAdd(&cnt[eidx[t]], 1);
  __syncthreads();
  if (tid == 0) {
    int run = 0;
    for (int e = 0; e < NE; ++e) { bas[e] = run; off[e] = run; run += cnt[e]; }
    bas[NE] = run;
    int n = 0;
    for (int e = 0; e < NE; ++e)
      for (int r0 = 0; r0 < cnt[e]; r0 += 64) {
        int rows = cnt[e] - r0; if (rows > 64) rows = 64;
        wl[n++] = make_int4(bas[e] + r0, rows, e, 0);
      }
    for (int r0 = 0; r0 < TOK; r0 += 64) wl[n++] = make_int4(r0, 64, NE, 0);
    *wl_n = n;
  }
  __syncthreads();
  for (int t = tid; t < TOK; t += 256) {
    const int e = eidx[t];
    const int p = atomicAdd(&off[e], 1);
    perm[p] = t;
    pos_of[t] = p;
  }
}

// ---------------- mlp1: barrier-free direct-to-register dual GEMM ----------------
// grid: bid = slot*16 + nt. Block = 4 waves; wave = M64 x N16 tile of both W1,W3 GEMMs.
__global__ __launch_bounds__(256) void mlp1_kernel(
    const bf16* __restrict__ x_bf,
    const float* __restrict__ W1, const float* __restrict__ W3,
    const float* __restrict__ Ws1, const float* __restrict__ Ws3,
    const int* __restrict__ perm, const int4* __restrict__ wl,
    const int* __restrict__ wl_n,
    bf16* __restrict__ h_r, bf16* __restrict__ h_s,
    float* __restrict__ ss_r, float* __restrict__ ss_z)
{
  const int bid = blockIdx.x;
  const int slot = bid >> 4, nt = bid & 15;
  if (slot >= *wl_n) return;
  const int4 wle = wl[slot];
  const int mbase = wle.x, rows = wle.y, eid = wle.z;
  const int tid = threadIdx.x;
  const bool routed = (eid < NE);
  const float* w1p = routed ? W1 + (size_t)eid * 1023 * 1024 : Ws1;
  const float* w3p = routed ? W3 + (size_t)eid * 1023 * 1024 : Ws3;
  bf16* hbuf  = routed ? h_r : h_s;
  float* ssbuf = routed ? ss_r : ss_z;
  const int n0 = nt * 64;

  __shared__ int toks[64];
  if (tid < 64) {
    int r = tid < rows ? tid : rows - 1;
    toks[tid] = routed ? perm[mbase + r] : (mbase + r);
  }
  __syncthreads();   // only barrier in the kernel

  const int wid = tid >> 6, lane = tid & 63;
  const int wc = wid * 16;
  const int lrow = lane & 15, quad = lane >> 4;

  const bf16* aP0 = x_bf + (size_t)toks[ 0 + lrow] * DD + quad * 8;
  const bf16* aP1 = x_bf + (size_t)toks[16 + lrow] * DD + quad * 8;
  const bf16* aP2 = x_bf + (size_t)toks[32 + lrow] * DD + quad * 8;
  const bf16* aP3 = x_bf + (size_t)toks[48 + lrow] * DD + quad * 8;

  int bn = n0 + wc + lrow; if (bn > 1022) bn = 1022;
  const float* b1P = w1p + (size_t)bn * 1024 + quad * 8;
  const float* b3P = w3p + (size_t)bn * 1024 + quad * 8;

  const floatx4 fz = {0.f, 0.f, 0.f, 0.f};
  floatx4 acc1[4], acc3[4];
#pragma unroll
  for (int mi = 0; mi < 4; ++mi) { acc1[mi] = fz; acc3[mi] = fz; }

#define LDA4(D,K) { D[0] = *(const bf16x8*)(aP0 + (K)); D[1] = *(const bf16x8*)(aP1 + (K)); \
                    D[2] = *(const bf16x8*)(aP2 + (K)); D[3] = *(const bf16x8*)(aP3 + (K)); }
#define LDB4(D,K) { D[0] = *(const float4*)(b1P + (K)); D[1] = *(const float4*)(b1P + (K) + 4); \
                    D[2] = *(const float4*)(b3P + (K)); D[3] = *(const float4*)(b3P + (K) + 4); }
#define CMP1(A,B) { bf16x8 b1f = pack_bf8v(B[0], B[1]); bf16x8 b3f = pack_bf8v(B[2], B[3]); \
  acc1[0] = MFMA16(A[0], b1f, acc1[0]); acc3[0] = MFMA16(A[0], b3f, acc3[0]); \
  acc1[1] = MFMA16(A[1], b1f, acc1[1]); acc3[1] = MFMA16(A[1], b3f, acc3[1]); \
  acc1[2] = MFMA16(A[2], b1f, acc1[2]); acc3[2] = MFMA16(A[2], b3f, acc3[2]); \
  acc1[3] = MFMA16(A[3], b1f, acc1[3]); acc3[3] = MFMA16(A[3], b3f, acc3[3]); }

  bf16x8 Aa[4], Ab[4], Ac[4], Ad[4];
  float4 Ba[4], Bb[4], Bc[4], Bd[4];
  LDA4(Aa, 0)  LDB4(Ba, 0)
  LDA4(Ab, 32) LDB4(Bb, 32)
  for (int k0 = 0; k0 < 1024; k0 += 128) {
    LDA4(Ac, (k0 +  64) & 1023)  LDB4(Bc, (k0 +  64) & 1023)
    CMP1(Aa, Ba)
    LDA4(Ad, (k0 +  96) & 1023)  LDB4(Bd, (k0 +  96) & 1023)
    CMP1(Ab, Bb)
    LDA4(Aa, (k0 + 128) & 1023)  LDB4(Ba, (k0 + 128) & 1023)
    CMP1(Ac, Bc)
    LDA4(Ab, (k0 + 160) & 1023)  LDB4(Bb, (k0 + 160) & 1023)
    CMP1(Ad, Bd)
  }
#undef LDA4
#undef LDB4
#undef CMP1

  const int n = n0 + wc + lrow;
#pragma unroll
  for (int mi = 0; mi < 4; ++mi) {
#pragma unroll
    for (int r = 0; r < 4; ++r) {
      const int row = mi * 16 + quad * 4 + r;
      const bool ok = (row < rows) && (n < 1023);
      const float s1 = acc1[mi][r];
      const float s3 = acc3[mi][r];
      const float sp = (s1 / (1.f + __expf(-s1))) * s3;
      float ssum = ok ? sp * sp : 0.f;
      if (ok) hbuf[(size_t)(mbase + row) * 1024 + 1 + n] = (bf16)sp;
      ssum += __shfl_xor(ssum, 1);
      ssum += __shfl_xor(ssum, 2);
      ssum += __shfl_xor(ssum, 4);
      ssum += __shfl_xor(ssum, 8);
      if (lrow == 0 && row < rows) atomicAdd(ssbuf + mbase + row, ssum);
    }
  }
}

// ---------------- mlp2: barrier-free direct-to-register GEMM (+fused time lift) ----------------
// grid: bid = slot*16 + nt. Block = 4 waves; wave = M64 x N16.
// h[:,0]=sqrt(ss+1) is patched into the k=0 A-fragment in-register.
__global__ __launch_bounds__(256) void mlp2_kernel(
    const bf16* __restrict__ h_r, const bf16* __restrict__ h_s,
    const float* __restrict__ W2, const float* __restrict__ Ws2,
    const int4* __restrict__ wl, const int* __restrict__ wl_n,
    const float* __restrict__ ss_r, const float* __restrict__ ss_z,
    float* __restrict__ o_r, float* __restrict__ o_s,
    float* __restrict__ ss_or, float* __restrict__ ss_oz)
{
  const int bid = blockIdx.x;
  const int slot = bid >> 4, nt = bid & 15;
  if (slot >= *wl_n) return;
  const int4 wle = wl[slot];
  const int mbase = wle.x, rows = wle.y, eid = wle.z;
  const int tid = threadIdx.x;
  const bool routed = (eid < NE);
  const float* wp = routed ? W2 + (size_t)eid * 1023 * 1024 : Ws2;
  const bf16* abuf = routed ? h_r : h_s;
  const float* ssmid = routed ? ss_r : ss_z;
  float* obuf  = routed ? o_r : o_s;
  float* ssbuf = routed ? ss_or : ss_oz;
  const int n0 = nt * 64;

  const int wid = tid >> 6, lane = tid & 63;
  const int wc = wid * 16;
  const int lrow = lane & 15, quad = lane >> 4;

  const bf16* aP[4];
  float tv[4];
#pragma unroll
  for (int mi = 0; mi < 4; ++mi) {
    int r = mi * 16 + lrow; if (r >= rows) r = rows - 1;
    aP[mi] = abuf + (size_t)(mbase + r) * 1024 + quad * 8;
    tv[mi] = sqrtf(ssmid[mbase + r] + 1.0f);
  }

  int bn = n0 + wc + lrow; if (bn > 1022) bn = 1022;
  const float* bP = wp + (size_t)bn * 1024 + quad * 8;

  const floatx4 fz = {0.f, 0.f, 0.f, 0.f};
  floatx4 acc[4];
#pragma unroll
  for (int mi = 0; mi < 4; ++mi) acc[mi] = fz;

#define LDA4(D,K) { D[0] = *(const bf16x8*)(aP[0] + (K)); D[1] = *(const bf16x8*)(aP[1] + (K)); \
                    D[2] = *(const bf16x8*)(aP[2] + (K)); D[3] = *(const bf16x8*)(aP[3] + (K)); }
#define LDB2(D,K) { D[0] = *(const float4*)(bP + (K)); D[1] = *(const float4*)(bP + (K) + 4); }
#define CMP2(A,B) { bf16x8 bfv = pack_bf8v(B[0], B[1]); \
  acc[0] = MFMA16(A[0], bfv, acc[0]); acc[1] = MFMA16(A[1], bfv, acc[1]); \
  acc[2] = MFMA16(A[2], bfv, acc[2]); acc[3] = MFMA16(A[3], bfv, acc[3]); }

  bf16x8 Aa[4], Ab[4], Ac[4], Ad[4];
  float4 Ba[2], Bb[2], Bc[2], Bd[2];
  LDA4(Aa, 0)  LDB2(Ba, 0)
  // patch time coordinate h[:,0] into k=0 fragment (element 0 of quad 0)
  if (quad == 0) {
#pragma unroll
    for (int mi = 0; mi < 4; ++mi) Aa[mi][0] = (bf16)tv[mi];
  }
  LDA4(Ab, 32) LDB2(Bb, 32)
  for (int k0 = 0; k0 < 1024; k0 += 128) {
    LDA4(Ac, (k0 +  64) & 1023)  LDB2(Bc, (k0 +  64) & 1023)
    CMP2(Aa, Ba)
    LDA4(Ad, (k0 +  96) & 1023)  LDB2(Bd, (k0 +  96) & 1023)
    CMP2(Ab, Bb)
    LDA4(Aa, (k0 + 128) & 1023)  LDB2(Ba, (k0 + 128) & 1023)
    CMP2(Ac, Bc)
    LDA4(Ab, (k0 + 160) & 1023)  LDB2(Bb, (k0 + 160) & 1023)
    CMP2(Ad, Bd)
  }
#undef LDA4
#undef LDB2
#undef CMP2

  const int n = n0 + wc + lrow;
#pragma unroll
  for (int mi = 0; mi < 4; ++mi) {
#pragma unroll
    for (int r = 0; r < 4; ++r) {
      const int row = mi * 16 + quad * 4 + r;
      const bool ok = (row < rows) && (n < 1023);
      const float v = acc[mi][r];
      float ssum = ok ? v * v : 0.f;
      if (ok) obuf[(size_t)(mbase + row) * 1024 + n] = v;
      ssum += __shfl_xor(ssum, 1);
      ssum += __shfl_xor(ssum, 2);
      ssum += __shfl_xor(ssum, 4);
      ssum += __shfl_xor(ssum, 8);
      if (lrow == 0 && row < rows) atomicAdd(ssbuf + mbase + row, ssum);
    }
  }
}

// ---------------- final LResNet combine + Lorentz normalize ----------------
__global__ __launch_bounds__(256) void combine_kernel(
    const float* __restrict__ o_r, const float* __restrict__ o_s,
    const float* __restrict__ ss_or, const float* __restrict__ ss_oz,
    const int* __restrict__ pos_of, const float* __restrict__ wgt,
    float* __restrict__ out)
{
  const int t = blockIdx.x, tid = threadIdx.x;
  const int p = pos_of[t];
  const float w = wgt[t];
  const float4 oz = ((const float4*)(o_s + (size_t)t * 1024))[tid];
  const float4 oe = ((const float4*)(o_r + (size_t)p * 1024))[tid];
  const float tw = 2.f * w;
  float c0 = oz.x + tw * oe.x;
  float c1 = oz.y + tw * oe.y;
  float c2 = oz.z + tw * oe.z;
  float c3 = (tid == 255) ? 0.f : (oz.w + tw * oe.w);  // n=1023 is padding
  float ssum = c0 * c0 + c1 * c1 + c2 * c2 + c3 * c3;
#pragma unroll
  for (int off = 32; off > 0; off >>= 1) ssum += __shfl_down(ssum, off);
  __shared__ float rs[4];
  if ((tid & 63) == 0) rs[tid >> 6] = ssum;
  __syncthreads();
  const float space2 = rs[0] + rs[1] + rs[2] + rs[3];
  const float comb0 = sqrtf(ss_oz[t] + 1.f) + 2.f + 2.f * w * sqrtf(ss_or[p] + 1.f);
  const float li = space2 - comb0 * comb0;
  const float inv = 1.f / sqrtf(fmaxf(fabsf(li), 1e-8f));
  float* orow = out + (size_t)t * 1024;
  const int j = 1 + tid * 4;
  orow[j]     = c0 * inv;
  orow[j + 1] = c1 * inv;
  orow[j + 2] = c2 * inv;
  if (tid != 255) orow[j + 3] = c3 * inv;
  if (tid == 0) orow[0] = comb0 * inv;
}

extern "C" void kernel_launch(void* const* d_in, const int* in_sizes, int n_in,
                              void* d_out, int out_size, void* d_ws, size_t ws_size,
                              hipStream_t stream) {
  const float* x      = (const float*)d_in[0];
  const float* gate_w = (const float*)d_in[1];
  const float* gate_b = (const float*)d_in[2];
  const float* W1     = (const float*)d_in[3];
  const float* W3     = (const float*)d_in[4];
  const float* W2     = (const float*)d_in[5];
  const float* Ws1    = (const float*)d_in[6];
  const float* Ws3    = (const float*)d_in[7];
  const float* Ws2    = (const float*)d_in[8];
  float* out = (float*)d_out;

  char* ws = (char*)d_ws;
  size_t off = 0;
  auto alloc = [&](size_t bytes) {
    void* p = ws + off;
    off += (bytes + 255) & ~(size_t)255;
    return p;
  };
  bf16*  x_bf = (bf16*) alloc((size_t)TOK * 1024 * 2);
  bf16*  h_r  = (bf16*) alloc((size_t)TOK * 1024 * 2);
  bf16*  h_s  = (bf16*) alloc((size_t)TOK * 1024 * 2);
  float* o_r  = (float*)alloc((size_t)TOK * 1024 * 4);
  float* o_s  = (float*)alloc((size_t)TOK * 1024 * 4);
  float* ss   = (float*)alloc((size_t)4 * TOK * 4);  // ss_r, ss_z, ss_or, ss_oz
  int*   eidx = (int*)  alloc((size_t)TOK * 4);
  float* ewgt = (float*)alloc((size_t)TOK * 4);
  int*   perm = (int*)  alloc((size_t)TOK * 4);
  int*   posf = (int*)  alloc((size_t)TOK * 4);
  int4*  wl   = (int4*) alloc((size_t)MAXSLOT * 16);
  int*   wln  = (int*)  alloc(16);

  float* ss_r  = ss;
  float* ss_z  = ss + TOK;
  float* ss_or = ss + 2 * TOK;
  float* ss_oz = ss + 3 * TOK;

  gate_cvt_kernel<<<TOK, 256, 0, stream>>>(x, gate_w, gate_b, x_bf, eidx, ewgt, ss);
  route_kernel<<<1, 256, 0, stream>>>(eidx, perm, posf, wl, wln);
  mlp1_kernel<<<MAXSLOT * 16, 256, 0, stream>>>(x_bf, W1, W3, Ws1, Ws3, perm, wl, wln,
                                                h_r, h_s, ss_r, ss_z);
  mlp2_kernel<<<MAXSLOT * 16, 256, 0, stream>>>(h_r, h_s, W2, Ws2, wl, wln,
                                                ss_r, ss_z, o_r, o_s, ss_or, ss_oz);
  combine_kernel<<<TOK, 256, 0, stream>>>(o_r, o_s, ss_or, ss_oz, posf, ewgt, out);
}

// Round 6
// 252.588 us; speedup vs baseline: 1.9539x; 1.9539x over previous
//
#include <hip/hip_runtime.h>

typedef __bf16 bf16;
typedef __attribute__((ext_vector_type(8))) __bf16 bf16x8;
typedef __attribute__((ext_vector_type(4))) float floatx4;

#define TOK 2048
#define DD  1024
#define NE  8
#define S1MAX 48   // mlp1 worklist slots (BM=128): <=24 routed + 16 shared
#define S2MAX 80   // mlp2 worklist slots (BM=64):  <=40 routed + 32 shared

#define MFMA16(A,B,C) __builtin_amdgcn_mfma_f32_16x16x32_bf16(A,B,C,0,0,0)

__device__ __forceinline__ void load_lds16(const bf16* g, bf16* l) {
  __builtin_amdgcn_global_load_lds(
      (const __attribute__((address_space(1))) void*)g,
      (__attribute__((address_space(3))) void*)l, 16, 0, 0);
}

__device__ __forceinline__ uint4 pack_bf8(float4 a, float4 b) {
  union { bf16 h[8]; uint4 u; } p;
  p.h[0] = (bf16)a.x; p.h[1] = (bf16)a.y; p.h[2] = (bf16)a.z; p.h[3] = (bf16)a.w;
  p.h[4] = (bf16)b.x; p.h[5] = (bf16)b.y; p.h[6] = (bf16)b.z; p.h[7] = (bf16)b.w;
  return p.u;
}

// ---------------- weight fp32 -> bf16 conversion (W1/W3 row-interleaved) ----------------
// rows: [0, 8*2046)   w13[e][2p+s][k]   (s=0:W1, s=1:W3)
//       [.., +2046)   ws13
//       [.., +8*1023) w2b
//       [.., +1023)   ws2b
#define NCVT (8*2046 + 2046 + 8*1023 + 1023)
__global__ __launch_bounds__(128) void convert_kernel(
    const float* __restrict__ W1, const float* __restrict__ W3,
    const float* __restrict__ W2, const float* __restrict__ Ws1,
    const float* __restrict__ Ws3, const float* __restrict__ Ws2,
    bf16* __restrict__ w13, bf16* __restrict__ ws13,
    bf16* __restrict__ w2b, bf16* __restrict__ ws2b)
{
  const int r = blockIdx.x, tid = threadIdx.x;
  const float* src; bf16* dst;
  if (r < 8 * 2046) {
    const int e = r / 2046, q = r % 2046;
    src = ((q & 1) ? W3 : W1) + ((size_t)e * 1023 + (q >> 1)) * 1024;
    dst = w13 + (size_t)r * 1024;
  } else if (r < 8 * 2046 + 2046) {
    const int q = r - 8 * 2046;
    src = ((q & 1) ? Ws3 : Ws1) + (size_t)(q >> 1) * 1024;
    dst = ws13 + (size_t)q * 1024;
  } else if (r < 8 * 2046 + 2046 + 8 * 1023) {
    const int q = r - (8 * 2046 + 2046);
    src = W2 + (size_t)q * 1024;
    dst = w2b + (size_t)q * 1024;
  } else {
    const int q = r - (8 * 2046 + 2046 + 8 * 1023);
    src = Ws2 + (size_t)q * 1024;
    dst = ws2b + (size_t)q * 1024;
  }
  const float4 f0 = ((const float4*)src)[tid * 2];
  const float4 f1 = ((const float4*)src)[tid * 2 + 1];
  ((uint4*)dst)[tid] = pack_bf8(f0, f1);
}

// ---------------- gate + x->bf16 + ss zero-init ----------------
__global__ __launch_bounds__(256) void gate_cvt_kernel(
    const float* __restrict__ x, const float* __restrict__ gate_w,
    const float* __restrict__ gate_b, bf16* __restrict__ x_bf,
    int* __restrict__ eidx, float* __restrict__ ewgt, float* __restrict__ ss)
{
  const int t = blockIdx.x, tid = threadIdx.x;
  if (tid < 4) ss[tid * TOK + t] = 0.f;
  const float4 v = ((const float4*)(x + (size_t)t * DD))[tid];
  union { bf16 h[4]; uint2 u; } pk;
  pk.h[0] = (bf16)v.x; pk.h[1] = (bf16)v.y; pk.h[2] = (bf16)v.z; pk.h[3] = (bf16)v.w;
  ((uint2*)(x_bf + (size_t)t * DD))[tid] = pk.u;

  float acc[NE];
#pragma unroll
  for (int e = 0; e < NE; ++e) acc[e] = 0.f;
  const float vv[4] = {v.x, v.y, v.z, v.w};
#pragma unroll
  for (int i = 0; i < 4; ++i) {
    const int d = tid * 4 + i;
    if (d >= 1) {
#pragma unroll
      for (int e = 0; e < NE; ++e) acc[e] += vv[i] * gate_w[e * (DD - 1) + d - 1];
    }
  }
#pragma unroll
  for (int off = 32; off > 0; off >>= 1) {
#pragma unroll
    for (int e = 0; e < NE; ++e) acc[e] += __shfl_down(acc[e], off);
  }
  __shared__ float red[4][NE];
  const int wid = tid >> 6, lane = tid & 63;
  if (lane == 0) {
#pragma unroll
    for (int e = 0; e < NE; ++e) red[wid][e] = acc[e];
  }
  __syncthreads();
  if (tid == 0) {
    float lg[NE];
#pragma unroll
    for (int e = 0; e < NE; ++e) lg[e] = red[0][e] + red[1][e] + red[2][e] + red[3][e];
    float m = lg[0];
    for (int e = 1; e < NE; ++e) m = fmaxf(m, lg[e]);
    float ex[NE], s = 0.f;
    for (int e = 0; e < NE; ++e) { ex[e] = expf(lg[e] - m); s += ex[e]; }
    const float inv = 1.f / s;
    int best = 0; float bb = ex[0] * inv + gate_b[0];
    for (int e = 1; e < NE; ++e) {
      const float b = ex[e] * inv + gate_b[e];
      if (b > bb) { bb = b; best = e; }
    }
    eidx[t] = best;
    ewgt[t] = ex[best] * inv;
  }
}

// ---------------- routing: count + prefix + scatter + two worklists ----------------
__global__ __launch_bounds__(256) void route_kernel(
    const int* __restrict__ eidx, int* __restrict__ perm,
    int* __restrict__ pos_of, int4* __restrict__ wl1, int* __restrict__ n1,
    int4* __restrict__ wl2, int* __restrict__ n2)
{
  __shared__ int cnt[NE], off[NE], bas[NE + 1];
  const int tid = threadIdx.x;
  if (tid < NE) cnt[tid] = 0;
  __syncthreads();
  for (int t = tid; t < TOK; t += 256) atomicAdd(&cnt[eidx[t]], 1);
  __syncthreads();
  if (tid == 0) {
    int run = 0;
    for (int e = 0; e < NE; ++e) { bas[e] = run; off[e] = run; run += cnt[e]; }
    bas[NE] = run;
    int n = 0;
    for (int e = 0; e < NE; ++e)
      for (int r0 = 0; r0 < cnt[e]; r0 += 128) {
        int rows = cnt[e] - r0; if (rows > 128) rows = 128;
        wl1[n++] = make_int4(bas[e] + r0, rows, e, 0);
      }
    for (int r0 = 0; r0 < TOK; r0 += 128) wl1[n++] = make_int4(r0, 128, NE, 0);
    *n1 = n;
    n = 0;
    for (int e = 0; e < NE; ++e)
      for (int r0 = 0; r0 < cnt[e]; r0 += 64) {
        int rows = cnt[e] - r0; if (rows > 64) rows = 64;
        wl2[n++] = make_int4(bas[e] + r0, rows, e, 0);
      }
    for (int r0 = 0; r0 < TOK; r0 += 64) wl2[n++] = make_int4(r0, 64, NE, 0);
    *n2 = n;
  }
  __syncthreads();
  for (int t = tid; t < TOK; t += 256) {
    const int e = eidx[t];
    const int p = atomicAdd(&off[e], 1);
    perm[p] = t;
    pos_of[t] = p;
  }
}

// ---------------- mlp1: BM=128 x BN=128(interleaved) x BK=64, global_load_lds ----------------
// grid: bid = slot*16 + nt. 4 waves, each 64x64 quadrant (4x4 MFMA x 2 kk).
__global__ __launch_bounds__(256) void mlp1_kernel(
    const bf16* __restrict__ x_bf, const bf16* __restrict__ w13,
    const bf16* __restrict__ ws13,
    const int* __restrict__ perm, const int4* __restrict__ wl,
    const int* __restrict__ wl_n,
    bf16* __restrict__ h_r, bf16* __restrict__ h_s,
    float* __restrict__ ss_r, float* __restrict__ ss_z)
{
  const int bid = blockIdx.x;
  const int slot = bid >> 4, nt = bid & 15;
  if (slot >= *wl_n) return;
  const int4 wle = wl[slot];
  const int mbase = wle.x, rows = wle.y, eid = wle.z;
  const int tid = threadIdx.x;
  const bool routed = (eid < NE);
  const bf16* bmat = routed ? w13 + (size_t)eid * 2046 * 1024 : ws13;
  bf16* hbuf  = routed ? h_r : h_s;
  float* ssbuf = routed ? ss_r : ss_z;

  __shared__ __align__(16) bf16 As[128 * 64];
  __shared__ __align__(16) bf16 Bs[128 * 64];
  __shared__ int toks[128];
  if (tid < 128) {
    int r = tid < rows ? tid : rows - 1;
    toks[tid] = routed ? perm[mbase + r] : (mbase + r);
  }
  __syncthreads();

  const int wid = tid >> 6, lane = tid & 63;
  // staging lane mapping: instr j stages 8 rows; lane i -> row base+i/8, lds k-slot i%8,
  // global k-block (i&7)^((i>>3)&7)  [XOR swizzle -> conflict-free ds_read]
  const int srow = lane >> 3;
  const int kbg  = (lane & 7) ^ (srow & 7);
  const bf16 *aG0, *aG1, *aG2, *aG3, *bG0, *bG1, *bG2, *bG3;
  bf16 *aL0, *aL1, *aL2, *aL3, *bL0, *bL1, *bL2, *bL3;
  {
    const int r0 = wid * 32;
    aG0 = x_bf + (size_t)toks[r0 +  0 + srow] * 1024 + kbg * 8;
    aG1 = x_bf + (size_t)toks[r0 +  8 + srow] * 1024 + kbg * 8;
    aG2 = x_bf + (size_t)toks[r0 + 16 + srow] * 1024 + kbg * 8;
    aG3 = x_bf + (size_t)toks[r0 + 24 + srow] * 1024 + kbg * 8;
    aL0 = As + (r0 +  0) * 64; aL1 = As + (r0 +  8) * 64;
    aL2 = As + (r0 + 16) * 64; aL3 = As + (r0 + 24) * 64;
    int b0 = nt * 128 + r0 + 0 + srow;  if (b0 > 2045) b0 = 2045;
    int b1 = nt * 128 + r0 + 8 + srow;  if (b1 > 2045) b1 = 2045;
    int b2 = nt * 128 + r0 + 16 + srow; if (b2 > 2045) b2 = 2045;
    int b3 = nt * 128 + r0 + 24 + srow; if (b3 > 2045) b3 = 2045;
    bG0 = bmat + (size_t)b0 * 1024 + kbg * 8;
    bG1 = bmat + (size_t)b1 * 1024 + kbg * 8;
    bG2 = bmat + (size_t)b2 * 1024 + kbg * 8;
    bG3 = bmat + (size_t)b3 * 1024 + kbg * 8;
    bL0 = Bs + (r0 +  0) * 64; bL1 = Bs + (r0 +  8) * 64;
    bL2 = Bs + (r0 + 16) * 64; bL3 = Bs + (r0 + 24) * 64;
  }

  const int lrow = lane & 15, quad = lane >> 4, sw = lane & 7;
  const int wrow = (wid >> 1) * 64, wcol = (wid & 1) * 64;
  int aoff[4], boff[4], koff[2];
#pragma unroll
  for (int mi = 0; mi < 4; ++mi) aoff[mi] = (wrow + mi * 16 + lrow) * 64;
#pragma unroll
  for (int ni = 0; ni < 4; ++ni) boff[ni] = (wcol + ni * 16 + lrow) * 64;
#pragma unroll
  for (int kk = 0; kk < 2; ++kk) koff[kk] = ((kk * 4 + quad) ^ sw) * 8;

  const floatx4 fz = {0.f, 0.f, 0.f, 0.f};
  floatx4 acc[4][4];
#pragma unroll
  for (int mi = 0; mi < 4; ++mi)
#pragma unroll
    for (int ni = 0; ni < 4; ++ni) acc[mi][ni] = fz;

  for (int ke = 0; ke < 1024; ke += 64) {
    load_lds16(aG0 + ke, aL0); load_lds16(aG1 + ke, aL1);
    load_lds16(aG2 + ke, aL2); load_lds16(aG3 + ke, aL3);
    load_lds16(bG0 + ke, bL0); load_lds16(bG1 + ke, bL1);
    load_lds16(bG2 + ke, bL2); load_lds16(bG3 + ke, bL3);
    __syncthreads();
#pragma unroll
    for (int kk = 0; kk < 2; ++kk) {
      bf16x8 av[4], bv[4];
#pragma unroll
      for (int mi = 0; mi < 4; ++mi) av[mi] = *(const bf16x8*)(As + aoff[mi] + koff[kk]);
#pragma unroll
      for (int ni = 0; ni < 4; ++ni) bv[ni] = *(const bf16x8*)(Bs + boff[ni] + koff[kk]);
#pragma unroll
      for (int mi = 0; mi < 4; ++mi)
#pragma unroll
        for (int ni = 0; ni < 4; ++ni)
          acc[mi][ni] = MFMA16(av[mi], bv[ni], acc[mi][ni]);
    }
    __syncthreads();
  }

  // epilogue: interleaved cols -> pair (s1,s3) via lane^1 shuffle, gate, store h(bf16), sumsq
#pragma unroll
  for (int mi = 0; mi < 4; ++mi) {
#pragma unroll
    for (int r = 0; r < 4; ++r) {
      const int row = wrow + mi * 16 + quad * 4 + r;
      const bool rowok = row < rows;
      float ssum = 0.f;
#pragma unroll
      for (int ni = 0; ni < 4; ++ni) {
        const float c = acc[mi][ni][r];
        const float partner = __shfl_xor(c, 1);
        const float s1 = (lane & 1) ? partner : c;
        const float s3 = (lane & 1) ? c : partner;
        const float sp = (s1 / (1.f + __expf(-s1))) * s3;
        const int P = (nt * 128 + wcol + ni * 16 + lrow) >> 1;
        const bool ok = rowok && ((lane & 1) == 0) && (P < 1023);
        if (ok) hbuf[(size_t)(mbase + row) * 1024 + 1 + P] = (bf16)sp;
        ssum += ok ? sp * sp : 0.f;
      }
      ssum += __shfl_xor(ssum, 1);
      ssum += __shfl_xor(ssum, 2);
      ssum += __shfl_xor(ssum, 4);
      ssum += __shfl_xor(ssum, 8);
      if (lrow == 0 && rowok) atomicAdd(ssbuf + mbase + row, ssum);
    }
  }
}

// ---------------- h[:,0] = sqrt(sumsq + 1) ----------------
__global__ __launch_bounds__(256) void finalize_t_kernel(
    const float* __restrict__ ss_r, const float* __restrict__ ss_z,
    bf16* __restrict__ h_r, bf16* __restrict__ h_s)
{
  const int i = blockIdx.x * 256 + threadIdx.x;
  if (i < TOK) {
    h_r[(size_t)i * 1024] = (bf16)sqrtf(ss_r[i] + 1.0f);
    h_s[(size_t)i * 1024] = (bf16)sqrtf(ss_z[i] + 1.0f);
  }
}

// ---------------- mlp2: BM=64 x BN=128 x BK=64, global_load_lds ----------------
// grid: bid = slot*8 + nt. 4 waves, each 32x64 quadrant (2x4 MFMA x 2 kk).
__global__ __launch_bounds__(256) void mlp2_kernel(
    const bf16* __restrict__ h_r, const bf16* __restrict__ h_s,
    const bf16* __restrict__ w2b, const bf16* __restrict__ ws2b,
    const int4* __restrict__ wl, const int* __restrict__ wl_n,
    float* __restrict__ o_r, float* __restrict__ o_s,
    float* __restrict__ ss_or, float* __restrict__ ss_oz)
{
  const int bid = blockIdx.x;
  const int slot = bid >> 3, nt = bid & 7;
  if (slot >= *wl_n) return;
  const int4 wle = wl[slot];
  const int mbase = wle.x, rows = wle.y, eid = wle.z;
  const int tid = threadIdx.x;
  const bool routed = (eid < NE);
  const bf16* abuf = routed ? h_r : h_s;
  const bf16* bmat = routed ? w2b + (size_t)eid * 1023 * 1024 : ws2b;
  float* obuf  = routed ? o_r : o_s;
  float* ssbuf = routed ? ss_or : ss_oz;
  const int n0 = nt * 128;

  __shared__ __align__(16) bf16 As[64 * 64];
  __shared__ __align__(16) bf16 Bs[128 * 64];

  const int wid = tid >> 6, lane = tid & 63;
  const int srow = lane >> 3;
  const int kbg  = (lane & 7) ^ (srow & 7);
  const bf16 *aG0, *aG1, *bG0, *bG1, *bG2, *bG3;
  bf16 *aL0, *aL1, *bL0, *bL1, *bL2, *bL3;
  {
    int ra0 = wid * 16 + 0 + srow; if (ra0 >= rows) ra0 = rows - 1;
    int ra1 = wid * 16 + 8 + srow; if (ra1 >= rows) ra1 = rows - 1;
    aG0 = abuf + (size_t)(mbase + ra0) * 1024 + kbg * 8;
    aG1 = abuf + (size_t)(mbase + ra1) * 1024 + kbg * 8;
    aL0 = As + (wid * 16 + 0) * 64;
    aL1 = As + (wid * 16 + 8) * 64;
    const int r0 = wid * 32;
    int b0 = n0 + r0 + 0 + srow;  if (b0 > 1022) b0 = 1022;
    int b1 = n0 + r0 + 8 + srow;  if (b1 > 1022) b1 = 1022;
    int b2 = n0 + r0 + 16 + srow; if (b2 > 1022) b2 = 1022;
    int b3 = n0 + r0 + 24 + srow; if (b3 > 1022) b3 = 1022;
    bG0 = bmat + (size_t)b0 * 1024 + kbg * 8;
    bG1 = bmat + (size_t)b1 * 1024 + kbg * 8;
    bG2 = bmat + (size_t)b2 * 1024 + kbg * 8;
    bG3 = bmat + (size_t)b3 * 1024 + kbg * 8;
    bL0 = Bs + (r0 +  0) * 64; bL1 = Bs + (r0 +  8) * 64;
    bL2 = Bs + (r0 + 16) * 64; bL3 = Bs + (r0 + 24) * 64;
  }

  const int lrow = lane & 15, quad = lane >> 4, sw = lane & 7;
  const int wrow = (wid >> 1) * 32, wcol = (wid & 1) * 64;
  int aoff[2], boff[4], koff[2];
#pragma unroll
  for (int mi = 0; mi < 2; ++mi) aoff[mi] = (wrow + mi * 16 + lrow) * 64;
#pragma unroll
  for (int ni = 0; ni < 4; ++ni) boff[ni] = (wcol + ni * 16 + lrow) * 64;
#pragma unroll
  for (int kk = 0; kk < 2; ++kk) koff[kk] = ((kk * 4 + quad) ^ sw) * 8;

  const floatx4 fz = {0.f, 0.f, 0.f, 0.f};
  floatx4 acc[2][4];
#pragma unroll
  for (int mi = 0; mi < 2; ++mi)
#pragma unroll
    for (int ni = 0; ni < 4; ++ni) acc[mi][ni] = fz;

  for (int ke = 0; ke < 1024; ke += 64) {
    load_lds16(aG0 + ke, aL0); load_lds16(aG1 + ke, aL1);
    load_lds16(bG0 + ke, bL0); load_lds16(bG1 + ke, bL1);
    load_lds16(bG2 + ke, bL2); load_lds16(bG3 + ke, bL3);
    __syncthreads();
#pragma unroll
    for (int kk = 0; kk < 2; ++kk) {
      bf16x8 av[2], bv[4];
#pragma unroll
      for (int mi = 0; mi < 2; ++mi) av[mi] = *(const bf16x8*)(As + aoff[mi] + koff[kk]);
#pragma unroll
      for (int ni = 0; ni < 4; ++ni) bv[ni] = *(const bf16x8*)(Bs + boff[ni] + koff[kk]);
#pragma unroll
      for (int mi = 0; mi < 2; ++mi)
#pragma unroll
        for (int ni = 0; ni < 4; ++ni)
          acc[mi][ni] = MFMA16(av[mi], bv[ni], acc[mi][ni]);
    }
    __syncthreads();
  }

#pragma unroll
  for (int mi = 0; mi < 2; ++mi) {
#pragma unroll
    for (int r = 0; r < 4; ++r) {
      const int row = wrow + mi * 16 + quad * 4 + r;
      const bool rowok = row < rows;
      float ssum = 0.f;
#pragma unroll
      for (int ni = 0; ni < 4; ++ni) {
        const float v = acc[mi][ni][r];
        const int n = n0 + wcol + ni * 16 + lrow;
        const bool ok = rowok && (n < 1023);
        if (ok) obuf[(size_t)(mbase + row) * 1024 + n] = v;
        ssum += ok ? v * v : 0.f;
      }
      ssum += __shfl_xor(ssum, 1);
      ssum += __shfl_xor(ssum, 2);
      ssum += __shfl_xor(ssum, 4);
      ssum += __shfl_xor(ssum, 8);
      if (lrow == 0 && rowok) atomicAdd(ssbuf + mbase + row, ssum);
    }
  }
}

// ---------------- final LResNet combine + Lorentz normalize ----------------
__global__ __launch_bounds__(256) void combine_kernel(
    const float* __restrict__ o_r, const float* __restrict__ o_s,
    const float* __restrict__ ss_or, const float* __restrict__ ss_oz,
    const int* __restrict__ pos_of, const float* __restrict__ wgt,
    float* __restrict__ out)
{
  const int t = blockIdx.x, tid = threadIdx.x;
  const int p = pos_of[t];
  const float w = wgt[t];
  const float4 oz = ((const float4*)(o_s + (size_t)t * 1024))[tid];
  const float4 oe = ((const float4*)(o_r + (size_t)p * 1024))[tid];
  const float tw = 2.f * w;
  float c0 = oz.x + tw * oe.x;
  float c1 = oz.y + tw * oe.y;
  float c2 = oz.z + tw * oe.z;
  float c3 = (tid == 255) ? 0.f : (oz.w + tw * oe.w);  // n=1023 is padding
  float ssum = c0 * c0 + c1 * c1 + c2 * c2 + c3 * c3;
#pragma unroll
  for (int off = 32; off > 0; off >>= 1) ssum += __shfl_down(ssum, off);
  __shared__ float rs[4];
  if ((tid & 63) == 0) rs[tid >> 6] = ssum;
  __syncthreads();
  const float space2 = rs[0] + rs[1] + rs[2] + rs[3];
  const float comb0 = sqrtf(ss_oz[t] + 1.f) + 2.f + 2.f * w * sqrtf(ss_or[p] + 1.f);
  const float li = space2 - comb0 * comb0;
  const float inv = 1.f / sqrtf(fmaxf(fabsf(li), 1e-8f));
  float* orow = out + (size_t)t * 1024;
  const int j = 1 + tid * 4;
  orow[j]     = c0 * inv;
  orow[j + 1] = c1 * inv;
  orow[j + 2] = c2 * inv;
  if (tid != 255) orow[j + 3] = c3 * inv;
  if (tid == 0) orow[0] = comb0 * inv;
}

extern "C" void kernel_launch(void* const* d_in, const int* in_sizes, int n_in,
                              void* d_out, int out_size, void* d_ws, size_t ws_size,
                              hipStream_t stream) {
  const float* x      = (const float*)d_in[0];
  const float* gate_w = (const float*)d_in[1];
  const float* gate_b = (const float*)d_in[2];
  const float* W1     = (const float*)d_in[3];
  const float* W3     = (const float*)d_in[4];
  const float* W2     = (const float*)d_in[5];
  const float* Ws1    = (const float*)d_in[6];
  const float* Ws3    = (const float*)d_in[7];
  const float* Ws2    = (const float*)d_in[8];
  float* out = (float*)d_out;

  char* ws = (char*)d_ws;
  size_t off = 0;
  auto alloc = [&](size_t bytes) {
    void* p = ws + off;
    off += (bytes + 255) & ~(size_t)255;
    return p;
  };
  bf16*  x_bf = (bf16*) alloc((size_t)TOK * 1024 * 2);
  bf16*  h_r  = (bf16*) alloc((size_t)TOK * 1024 * 2);
  bf16*  h_s  = (bf16*) alloc((size_t)TOK * 1024 * 2);
  float* o_r  = (float*)alloc((size_t)TOK * 1024 * 4);
  float* o_s  = (float*)alloc((size_t)TOK * 1024 * 4);
  float* ss   = (float*)alloc((size_t)4 * TOK * 4);
  int*   eidx = (int*)  alloc((size_t)TOK * 4);
  float* ewgt = (float*)alloc((size_t)TOK * 4);
  int*   perm = (int*)  alloc((size_t)TOK * 4);
  int*   posf = (int*)  alloc((size_t)TOK * 4);
  int4*  wl1  = (int4*) alloc((size_t)S1MAX * 16);
  int4*  wl2  = (int4*) alloc((size_t)S2MAX * 16);
  int*   wn   = (int*)  alloc(32);
  bf16*  w13  = (bf16*) alloc((size_t)8 * 2046 * 1024 * 2);
  bf16*  ws13 = (bf16*) alloc((size_t)2046 * 1024 * 2);
  bf16*  w2b  = (bf16*) alloc((size_t)8 * 1023 * 1024 * 2);
  bf16*  ws2b = (bf16*) alloc((size_t)1023 * 1024 * 2);

  float* ss_r  = ss;
  float* ss_z  = ss + TOK;
  float* ss_or = ss + 2 * TOK;
  float* ss_oz = ss + 3 * TOK;

  convert_kernel<<<NCVT, 128, 0, stream>>>(W1, W3, W2, Ws1, Ws3, Ws2,
                                           w13, ws13, w2b, ws2b);
  gate_cvt_kernel<<<TOK, 256, 0, stream>>>(x, gate_w, gate_b, x_bf, eidx, ewgt, ss);
  route_kernel<<<1, 256, 0, stream>>>(eidx, perm, posf, wl1, wn, wl2, wn + 1);
  mlp1_kernel<<<S1MAX * 16, 256, 0, stream>>>(x_bf, w13, ws13, perm, wl1, wn,
                                              h_r, h_s, ss_r, ss_z);
  finalize_t_kernel<<<8, 256, 0, stream>>>(ss_r, ss_z, h_r, h_s);
  mlp2_kernel<<<S2MAX * 8, 256, 0, stream>>>(h_r, h_s, w2b, ws2b, wl2, wn + 1,
                                             o_r, o_s, ss_or, ss_oz);
  combine_kernel<<<TOK, 256, 0, stream>>>(o_r, o_s, ss_or, ss_oz, posf, ewgt, out);
}

// Round 7
// 248.367 us; speedup vs baseline: 1.9871x; 1.0170x over previous
//
#include <hip/hip_runtime.h>

typedef __bf16 bf16;
typedef __attribute__((ext_vector_type(8))) __bf16 bf16x8;
typedef __attribute__((ext_vector_type(4))) float floatx4;

#define TOK 2048
#define DD  1024
#define NE  8
#define S1MAX 48   // mlp1 worklist slots (BM=128): <=24 routed + 16 shared
#define S2MAX 80   // mlp2 worklist slots (BM=64):  <=40 routed + 32 shared

#define MFMA16(A,B,C) __builtin_amdgcn_mfma_f32_16x16x32_bf16(A,B,C,0,0,0)

__device__ __forceinline__ void load_lds16(const bf16* g, bf16* l) {
  __builtin_amdgcn_global_load_lds(
      (const __attribute__((address_space(1))) void*)g,
      (__attribute__((address_space(3))) void*)l, 16, 0, 0);
}

// fine-grained barrier: wait only the OLDEST outstanding loads, keep N in flight
#define WBAR(N) asm volatile("s_waitcnt vmcnt(" #N ")\n\ts_barrier" ::: "memory")
#define BARO    asm volatile("s_barrier" ::: "memory")

__device__ __forceinline__ uint4 pack_bf8(float4 a, float4 b) {
  union { bf16 h[8]; uint4 u; } p;
  p.h[0] = (bf16)a.x; p.h[1] = (bf16)a.y; p.h[2] = (bf16)a.z; p.h[3] = (bf16)a.w;
  p.h[4] = (bf16)b.x; p.h[5] = (bf16)b.y; p.h[6] = (bf16)b.z; p.h[7] = (bf16)b.w;
  return p.u;
}

// ---------------- weight fp32 -> bf16 conversion (W1/W3 row-interleaved) ----------------
#define NCVT (8*2046 + 2046 + 8*1023 + 1023)
__global__ __launch_bounds__(128) void convert_kernel(
    const float* __restrict__ W1, const float* __restrict__ W3,
    const float* __restrict__ W2, const float* __restrict__ Ws1,
    const float* __restrict__ Ws3, const float* __restrict__ Ws2,
    bf16* __restrict__ w13, bf16* __restrict__ ws13,
    bf16* __restrict__ w2b, bf16* __restrict__ ws2b)
{
  const int r = blockIdx.x, tid = threadIdx.x;
  const float* src; bf16* dst;
  if (r < 8 * 2046) {
    const int e = r / 2046, q = r % 2046;
    src = ((q & 1) ? W3 : W1) + ((size_t)e * 1023 + (q >> 1)) * 1024;
    dst = w13 + (size_t)r * 1024;
  } else if (r < 8 * 2046 + 2046) {
    const int q = r - 8 * 2046;
    src = ((q & 1) ? Ws3 : Ws1) + (size_t)(q >> 1) * 1024;
    dst = ws13 + (size_t)q * 1024;
  } else if (r < 8 * 2046 + 2046 + 8 * 1023) {
    const int q = r - (8 * 2046 + 2046);
    src = W2 + (size_t)q * 1024;
    dst = w2b + (size_t)q * 1024;
  } else {
    const int q = r - (8 * 2046 + 2046 + 8 * 1023);
    src = Ws2 + (size_t)q * 1024;
    dst = ws2b + (size_t)q * 1024;
  }
  const float4 f0 = ((const float4*)src)[tid * 2];
  const float4 f1 = ((const float4*)src)[tid * 2 + 1];
  ((uint4*)dst)[tid] = pack_bf8(f0, f1);
}

// ---------------- gate + x->bf16 + ss zero-init ----------------
__global__ __launch_bounds__(256) void gate_cvt_kernel(
    const float* __restrict__ x, const float* __restrict__ gate_w,
    const float* __restrict__ gate_b, bf16* __restrict__ x_bf,
    int* __restrict__ eidx, float* __restrict__ ewgt, float* __restrict__ ss)
{
  const int t = blockIdx.x, tid = threadIdx.x;
  if (tid < 4) ss[tid * TOK + t] = 0.f;
  const float4 v = ((const float4*)(x + (size_t)t * DD))[tid];
  union { bf16 h[4]; uint2 u; } pk;
  pk.h[0] = (bf16)v.x; pk.h[1] = (bf16)v.y; pk.h[2] = (bf16)v.z; pk.h[3] = (bf16)v.w;
  ((uint2*)(x_bf + (size_t)t * DD))[tid] = pk.u;

  float acc[NE];
#pragma unroll
  for (int e = 0; e < NE; ++e) acc[e] = 0.f;
  const float vv[4] = {v.x, v.y, v.z, v.w};
#pragma unroll
  for (int i = 0; i < 4; ++i) {
    const int d = tid * 4 + i;
    if (d >= 1) {
#pragma unroll
      for (int e = 0; e < NE; ++e) acc[e] += vv[i] * gate_w[e * (DD - 1) + d - 1];
    }
  }
#pragma unroll
  for (int off = 32; off > 0; off >>= 1) {
#pragma unroll
    for (int e = 0; e < NE; ++e) acc[e] += __shfl_down(acc[e], off);
  }
  __shared__ float red[4][NE];
  const int wid = tid >> 6, lane = tid & 63;
  if (lane == 0) {
#pragma unroll
    for (int e = 0; e < NE; ++e) red[wid][e] = acc[e];
  }
  __syncthreads();
  if (tid == 0) {
    float lg[NE];
#pragma unroll
    for (int e = 0; e < NE; ++e) lg[e] = red[0][e] + red[1][e] + red[2][e] + red[3][e];
    float m = lg[0];
    for (int e = 1; e < NE; ++e) m = fmaxf(m, lg[e]);
    float ex[NE], s = 0.f;
    for (int e = 0; e < NE; ++e) { ex[e] = expf(lg[e] - m); s += ex[e]; }
    const float inv = 1.f / s;
    int best = 0; float bb = ex[0] * inv + gate_b[0];
    for (int e = 1; e < NE; ++e) {
      const float b = ex[e] * inv + gate_b[e];
      if (b > bb) { bb = b; best = e; }
    }
    eidx[t] = best;
    ewgt[t] = ex[best] * inv;
  }
}

// ---------------- routing: count + prefix + scatter + two worklists ----------------
__global__ __launch_bounds__(256) void route_kernel(
    const int* __restrict__ eidx, int* __restrict__ perm,
    int* __restrict__ pos_of, int4* __restrict__ wl1, int* __restrict__ n1,
    int4* __restrict__ wl2, int* __restrict__ n2)
{
  __shared__ int cnt[NE], off[NE], bas[NE + 1];
  const int tid = threadIdx.x;
  if (tid < NE) cnt[tid] = 0;
  __syncthreads();
  for (int t = tid; t < TOK; t += 256) atomicAdd(&cnt[eidx[t]], 1);
  __syncthreads();
  if (tid == 0) {
    int run = 0;
    for (int e = 0; e < NE; ++e) { bas[e] = run; off[e] = run; run += cnt[e]; }
    bas[NE] = run;
    int n = 0;
    for (int e = 0; e < NE; ++e)
      for (int r0 = 0; r0 < cnt[e]; r0 += 128) {
        int rows = cnt[e] - r0; if (rows > 128) rows = 128;
        wl1[n++] = make_int4(bas[e] + r0, rows, e, 0);
      }
    for (int r0 = 0; r0 < TOK; r0 += 128) wl1[n++] = make_int4(r0, 128, NE, 0);
    *n1 = n;
    n = 0;
    for (int e = 0; e < NE; ++e)
      for (int r0 = 0; r0 < cnt[e]; r0 += 64) {
        int rows = cnt[e] - r0; if (rows > 64) rows = 64;
        wl2[n++] = make_int4(bas[e] + r0, rows, e, 0);
      }
    for (int r0 = 0; r0 < TOK; r0 += 64) wl2[n++] = make_int4(r0, 64, NE, 0);
    *n2 = n;
  }
  __syncthreads();
  for (int t = tid; t < TOK; t += 256) {
    const int e = eidx[t];
    const int p = atomicAdd(&off[e], 1);
    perm[p] = t;
    pos_of[t] = p;
  }
}

// ---------------- mlp1: BM=128 x BN=128(interleaved) x BK=64, dbuf + vmcnt(8) pipeline ----------------
__global__ __launch_bounds__(256) void mlp1_kernel(
    const bf16* __restrict__ x_bf, const bf16* __restrict__ w13,
    const bf16* __restrict__ ws13,
    const int* __restrict__ perm, const int4* __restrict__ wl,
    const int* __restrict__ wl_n,
    bf16* __restrict__ h_r, bf16* __restrict__ h_s,
    float* __restrict__ ss_r, float* __restrict__ ss_z)
{
  const int bid = blockIdx.x;
  const int slot = bid >> 4, nt = bid & 15;
  if (slot >= *wl_n) return;
  const int4 wle = wl[slot];
  const int mbase = wle.x, rows = wle.y, eid = wle.z;
  const int tid = threadIdx.x;
  const bool routed = (eid < NE);
  const bf16* bmat = routed ? w13 + (size_t)eid * 2046 * 1024 : ws13;
  bf16* hbuf  = routed ? h_r : h_s;
  float* ssbuf = routed ? ss_r : ss_z;

  __shared__ __align__(16) bf16 As[2][128 * 64];
  __shared__ __align__(16) bf16 Bs[2][128 * 64];
  __shared__ int toks[128];
  if (tid < 128) {
    int r = tid < rows ? tid : rows - 1;
    toks[tid] = routed ? perm[mbase + r] : (mbase + r);
  }
  __syncthreads();

  const int wid = tid >> 6, lane = tid & 63;
  const int srow = lane >> 3;
  const int kbg  = (lane & 7) ^ (srow & 7);
  const bf16 *aG0, *aG1, *aG2, *aG3, *bG0, *bG1, *bG2, *bG3;
  int aL0o, aL1o, aL2o, aL3o, bL0o, bL1o, bL2o, bL3o;
  {
    const int r0 = wid * 32;
    aG0 = x_bf + (size_t)toks[r0 +  0 + srow] * 1024 + kbg * 8;
    aG1 = x_bf + (size_t)toks[r0 +  8 + srow] * 1024 + kbg * 8;
    aG2 = x_bf + (size_t)toks[r0 + 16 + srow] * 1024 + kbg * 8;
    aG3 = x_bf + (size_t)toks[r0 + 24 + srow] * 1024 + kbg * 8;
    aL0o = (r0 +  0) * 64; aL1o = (r0 +  8) * 64;
    aL2o = (r0 + 16) * 64; aL3o = (r0 + 24) * 64;
    int b0 = nt * 128 + r0 + 0 + srow;  if (b0 > 2045) b0 = 2045;
    int b1 = nt * 128 + r0 + 8 + srow;  if (b1 > 2045) b1 = 2045;
    int b2 = nt * 128 + r0 + 16 + srow; if (b2 > 2045) b2 = 2045;
    int b3 = nt * 128 + r0 + 24 + srow; if (b3 > 2045) b3 = 2045;
    bG0 = bmat + (size_t)b0 * 1024 + kbg * 8;
    bG1 = bmat + (size_t)b1 * 1024 + kbg * 8;
    bG2 = bmat + (size_t)b2 * 1024 + kbg * 8;
    bG3 = bmat + (size_t)b3 * 1024 + kbg * 8;
    bL0o = (r0 +  0) * 64; bL1o = (r0 +  8) * 64;
    bL2o = (r0 + 16) * 64; bL3o = (r0 + 24) * 64;
  }

  const int lrow = lane & 15, quad = lane >> 4, sw = lane & 7;
  const int wrow = (wid >> 1) * 64, wcol = (wid & 1) * 64;
  int aoff[4], boff[4], koff[2];
#pragma unroll
  for (int mi = 0; mi < 4; ++mi) aoff[mi] = (wrow + mi * 16 + lrow) * 64;
#pragma unroll
  for (int ni = 0; ni < 4; ++ni) boff[ni] = (wcol + ni * 16 + lrow) * 64;
#pragma unroll
  for (int kk = 0; kk < 2; ++kk) koff[kk] = ((kk * 4 + quad) ^ sw) * 8;

  const floatx4 fz = {0.f, 0.f, 0.f, 0.f};
  floatx4 acc[4][4];
#pragma unroll
  for (int mi = 0; mi < 4; ++mi)
#pragma unroll
    for (int ni = 0; ni < 4; ++ni) acc[mi][ni] = fz;

#define STAGE1(KE, BUF) { \
    load_lds16(aG0 + (KE), As[BUF] + aL0o); load_lds16(aG1 + (KE), As[BUF] + aL1o); \
    load_lds16(aG2 + (KE), As[BUF] + aL2o); load_lds16(aG3 + (KE), As[BUF] + aL3o); \
    load_lds16(bG0 + (KE), Bs[BUF] + bL0o); load_lds16(bG1 + (KE), Bs[BUF] + bL1o); \
    load_lds16(bG2 + (KE), Bs[BUF] + bL2o); load_lds16(bG3 + (KE), Bs[BUF] + bL3o); }

#define COMP1(BUF) { \
_Pragma("unroll") \
    for (int kk = 0; kk < 2; ++kk) { \
      bf16x8 av[4], bv[4]; \
_Pragma("unroll") \
      for (int mi = 0; mi < 4; ++mi) av[mi] = *(const bf16x8*)(As[BUF] + aoff[mi] + koff[kk]); \
_Pragma("unroll") \
      for (int ni = 0; ni < 4; ++ni) bv[ni] = *(const bf16x8*)(Bs[BUF] + boff[ni] + koff[kk]); \
_Pragma("unroll") \
      for (int mi = 0; mi < 4; ++mi) \
_Pragma("unroll") \
        for (int ni = 0; ni < 4; ++ni) \
          acc[mi][ni] = MFMA16(av[mi], bv[ni], acc[mi][ni]); \
    } }

  STAGE1(0, 0)
  STAGE1(64, 1)
#pragma unroll 1
  for (int t = 0; t < 7; ++t) {
    const int ke = t * 128;
    WBAR(8); COMP1(0) BARO; STAGE1(ke + 128, 0)
    WBAR(8); COMP1(1) BARO; STAGE1(ke + 192, 1)
  }
  WBAR(8); COMP1(0)   // iter 14 (loads of iter 15 remain in flight)
  WBAR(0); COMP1(1)   // iter 15
#undef STAGE1
#undef COMP1

  // epilogue: interleaved cols -> (s1,s3) via lane^1 shuffle, gate, store h(bf16), sumsq
#pragma unroll
  for (int mi = 0; mi < 4; ++mi) {
#pragma unroll
    for (int r = 0; r < 4; ++r) {
      const int row = wrow + mi * 16 + quad * 4 + r;
      const bool rowok = row < rows;
      float ssum = 0.f;
#pragma unroll
      for (int ni = 0; ni < 4; ++ni) {
        const float c = acc[mi][ni][r];
        const float partner = __shfl_xor(c, 1);
        const float s1 = (lane & 1) ? partner : c;
        const float s3 = (lane & 1) ? c : partner;
        const float sp = (s1 / (1.f + __expf(-s1))) * s3;
        const int P = (nt * 128 + wcol + ni * 16 + lrow) >> 1;
        const bool ok = rowok && ((lane & 1) == 0) && (P < 1023);
        if (ok) hbuf[(size_t)(mbase + row) * 1024 + 1 + P] = (bf16)sp;
        ssum += ok ? sp * sp : 0.f;
      }
      ssum += __shfl_xor(ssum, 1);
      ssum += __shfl_xor(ssum, 2);
      ssum += __shfl_xor(ssum, 4);
      ssum += __shfl_xor(ssum, 8);
      if (lrow == 0 && rowok) atomicAdd(ssbuf + mbase + row, ssum);
    }
  }
}

// ---------------- h[:,0] = sqrt(sumsq + 1) ----------------
__global__ __launch_bounds__(256) void finalize_t_kernel(
    const float* __restrict__ ss_r, const float* __restrict__ ss_z,
    bf16* __restrict__ h_r, bf16* __restrict__ h_s)
{
  const int i = blockIdx.x * 256 + threadIdx.x;
  if (i < TOK) {
    h_r[(size_t)i * 1024] = (bf16)sqrtf(ss_r[i] + 1.0f);
    h_s[(size_t)i * 1024] = (bf16)sqrtf(ss_z[i] + 1.0f);
  }
}

// ---------------- mlp2: BM=64 x BN=128 x BK=64, dbuf + vmcnt(6) pipeline ----------------
__global__ __launch_bounds__(256) void mlp2_kernel(
    const bf16* __restrict__ h_r, const bf16* __restrict__ h_s,
    const bf16* __restrict__ w2b, const bf16* __restrict__ ws2b,
    const int4* __restrict__ wl, const int* __restrict__ wl_n,
    float* __restrict__ o_r, float* __restrict__ o_s,
    float* __restrict__ ss_or, float* __restrict__ ss_oz)
{
  const int bid = blockIdx.x;
  const int slot = bid >> 3, nt = bid & 7;
  if (slot >= *wl_n) return;
  const int4 wle = wl[slot];
  const int mbase = wle.x, rows = wle.y, eid = wle.z;
  const int tid = threadIdx.x;
  const bool routed = (eid < NE);
  const bf16* abuf = routed ? h_r : h_s;
  const bf16* bmat = routed ? w2b + (size_t)eid * 1023 * 1024 : ws2b;
  float* obuf  = routed ? o_r : o_s;
  float* ssbuf = routed ? ss_or : ss_oz;
  const int n0 = nt * 128;

  __shared__ __align__(16) bf16 As[2][64 * 64];
  __shared__ __align__(16) bf16 Bs[2][128 * 64];

  const int wid = tid >> 6, lane = tid & 63;
  const int srow = lane >> 3;
  const int kbg  = (lane & 7) ^ (srow & 7);
  const bf16 *aG0, *aG1, *bG0, *bG1, *bG2, *bG3;
  int aL0o, aL1o, bL0o, bL1o, bL2o, bL3o;
  {
    int ra0 = wid * 16 + 0 + srow; if (ra0 >= rows) ra0 = rows - 1;
    int ra1 = wid * 16 + 8 + srow; if (ra1 >= rows) ra1 = rows - 1;
    aG0 = abuf + (size_t)(mbase + ra0) * 1024 + kbg * 8;
    aG1 = abuf + (size_t)(mbase + ra1) * 1024 + kbg * 8;
    aL0o = (wid * 16 + 0) * 64;
    aL1o = (wid * 16 + 8) * 64;
    const int r0 = wid * 32;
    int b0 = n0 + r0 + 0 + srow;  if (b0 > 1022) b0 = 1022;
    int b1 = n0 + r0 + 8 + srow;  if (b1 > 1022) b1 = 1022;
    int b2 = n0 + r0 + 16 + srow; if (b2 > 1022) b2 = 1022;
    int b3 = n0 + r0 + 24 + srow; if (b3 > 1022) b3 = 1022;
    bG0 = bmat + (size_t)b0 * 1024 + kbg * 8;
    bG1 = bmat + (size_t)b1 * 1024 + kbg * 8;
    bG2 = bmat + (size_t)b2 * 1024 + kbg * 8;
    bG3 = bmat + (size_t)b3 * 1024 + kbg * 8;
    bL0o = (r0 +  0) * 64; bL1o = (r0 +  8) * 64;
    bL2o = (r0 + 16) * 64; bL3o = (r0 + 24) * 64;
  }

  const int lrow = lane & 15, quad = lane >> 4, sw = lane & 7;
  const int wrow = (wid >> 1) * 32, wcol = (wid & 1) * 64;
  int aoff[2], boff[4], koff[2];
#pragma unroll
  for (int mi = 0; mi < 2; ++mi) aoff[mi] = (wrow + mi * 16 + lrow) * 64;
#pragma unroll
  for (int ni = 0; ni < 4; ++ni) boff[ni] = (wcol + ni * 16 + lrow) * 64;
#pragma unroll
  for (int kk = 0; kk < 2; ++kk) koff[kk] = ((kk * 4 + quad) ^ sw) * 8;

  const floatx4 fz = {0.f, 0.f, 0.f, 0.f};
  floatx4 acc[2][4];
#pragma unroll
  for (int mi = 0; mi < 2; ++mi)
#pragma unroll
    for (int ni = 0; ni < 4; ++ni) acc[mi][ni] = fz;

#define STAGE2(KE, BUF) { \
    load_lds16(aG0 + (KE), As[BUF] + aL0o); load_lds16(aG1 + (KE), As[BUF] + aL1o); \
    load_lds16(bG0 + (KE), Bs[BUF] + bL0o); load_lds16(bG1 + (KE), Bs[BUF] + bL1o); \
    load_lds16(bG2 + (KE), Bs[BUF] + bL2o); load_lds16(bG3 + (KE), Bs[BUF] + bL3o); }

#define COMP2(BUF) { \
_Pragma("unroll") \
    for (int kk = 0; kk < 2; ++kk) { \
      bf16x8 av[2], bv[4]; \
_Pragma("unroll") \
      for (int mi = 0; mi < 2; ++mi) av[mi] = *(const bf16x8*)(As[BUF] + aoff[mi] + koff[kk]); \
_Pragma("unroll") \
      for (int ni = 0; ni < 4; ++ni) bv[ni] = *(const bf16x8*)(Bs[BUF] + boff[ni] + koff[kk]); \
_Pragma("unroll") \
      for (int mi = 0; mi < 2; ++mi) \
_Pragma("unroll") \
        for (int ni = 0; ni < 4; ++ni) \
          acc[mi][ni] = MFMA16(av[mi], bv[ni], acc[mi][ni]); \
    } }

  STAGE2(0, 0)
  STAGE2(64, 1)
#pragma unroll 1
  for (int t = 0; t < 7; ++t) {
    const int ke = t * 128;
    WBAR(6); COMP2(0) BARO; STAGE2(ke + 128, 0)
    WBAR(6); COMP2(1) BARO; STAGE2(ke + 192, 1)
  }
  WBAR(6); COMP2(0)
  WBAR(0); COMP2(1)
#undef STAGE2
#undef COMP2

#pragma unroll
  for (int mi = 0; mi < 2; ++mi) {
#pragma unroll
    for (int r = 0; r < 4; ++r) {
      const int row = wrow + mi * 16 + quad * 4 + r;
      const bool rowok = row < rows;
      float ssum = 0.f;
#pragma unroll
      for (int ni = 0; ni < 4; ++ni) {
        const float v = acc[mi][ni][r];
        const int n = n0 + wcol + ni * 16 + lrow;
        const bool ok = rowok && (n < 1023);
        if (ok) obuf[(size_t)(mbase + row) * 1024 + n] = v;
        ssum += ok ? v * v : 0.f;
      }
      ssum += __shfl_xor(ssum, 1);
      ssum += __shfl_xor(ssum, 2);
      ssum += __shfl_xor(ssum, 4);
      ssum += __shfl_xor(ssum, 8);
      if (lrow == 0 && rowok) atomicAdd(ssbuf + mbase + row, ssum);
    }
  }
}

// ---------------- final LResNet combine + Lorentz normalize ----------------
__global__ __launch_bounds__(256) void combine_kernel(
    const float* __restrict__ o_r, const float* __restrict__ o_s,
    const float* __restrict__ ss_or, const float* __restrict__ ss_oz,
    const int* __restrict__ pos_of, const float* __restrict__ wgt,
    float* __restrict__ out)
{
  const int t = blockIdx.x, tid = threadIdx.x;
  const int p = pos_of[t];
  const float w = wgt[t];
  const float4 oz = ((const float4*)(o_s + (size_t)t * 1024))[tid];
  const float4 oe = ((const float4*)(o_r + (size_t)p * 1024))[tid];
  const float tw = 2.f * w;
  float c0 = oz.x + tw * oe.x;
  float c1 = oz.y + tw * oe.y;
  float c2 = oz.z + tw * oe.z;
  float c3 = (tid == 255) ? 0.f : (oz.w + tw * oe.w);  // n=1023 is padding
  float ssum = c0 * c0 + c1 * c1 + c2 * c2 + c3 * c3;
#pragma unroll
  for (int off = 32; off > 0; off >>= 1) ssum += __shfl_down(ssum, off);
  __shared__ float rs[4];
  if ((tid & 63) == 0) rs[tid >> 6] = ssum;
  __syncthreads();
  const float space2 = rs[0] + rs[1] + rs[2] + rs[3];
  const float comb0 = sqrtf(ss_oz[t] + 1.f) + 2.f + 2.f * w * sqrtf(ss_or[p] + 1.f);
  const float li = space2 - comb0 * comb0;
  const float inv = 1.f / sqrtf(fmaxf(fabsf(li), 1e-8f));
  float* orow = out + (size_t)t * 1024;
  const int j = 1 + tid * 4;
  orow[j]     = c0 * inv;
  orow[j + 1] = c1 * inv;
  orow[j + 2] = c2 * inv;
  if (tid != 255) orow[j + 3] = c3 * inv;
  if (tid == 0) orow[0] = comb0 * inv;
}

extern "C" void kernel_launch(void* const* d_in, const int* in_sizes, int n_in,
                              void* d_out, int out_size, void* d_ws, size_t ws_size,
                              hipStream_t stream) {
  const float* x      = (const float*)d_in[0];
  const float* gate_w = (const float*)d_in[1];
  const float* gate_b = (const float*)d_in[2];
  const float* W1     = (const float*)d_in[3];
  const float* W3     = (const float*)d_in[4];
  const float* W2     = (const float*)d_in[5];
  const float* Ws1    = (const float*)d_in[6];
  const float* Ws3    = (const float*)d_in[7];
  const float* Ws2    = (const float*)d_in[8];
  float* out = (float*)d_out;

  char* ws = (char*)d_ws;
  size_t off = 0;
  auto alloc = [&](size_t bytes) {
    void* p = ws + off;
    off += (bytes + 255) & ~(size_t)255;
    return p;
  };
  bf16*  x_bf = (bf16*) alloc((size_t)TOK * 1024 * 2);
  bf16*  h_r  = (bf16*) alloc((size_t)TOK * 1024 * 2);
  bf16*  h_s  = (bf16*) alloc((size_t)TOK * 1024 * 2);
  float* o_r  = (float*)alloc((size_t)TOK * 1024 * 4);
  float* o_s  = (float*)alloc((size_t)TOK * 1024 * 4);
  float* ss   = (float*)alloc((size_t)4 * TOK * 4);
  int*   eidx = (int*)  alloc((size_t)TOK * 4);
  float* ewgt = (float*)alloc((size_t)TOK * 4);
  int*   perm = (int*)  alloc((size_t)TOK * 4);
  int*   posf = (int*)  alloc((size_t)TOK * 4);
  int4*  wl1  = (int4*) alloc((size_t)S1MAX * 16);
  int4*  wl2  = (int4*) alloc((size_t)S2MAX * 16);
  int*   wn   = (int*)  alloc(32);
  bf16*  w13  = (bf16*) alloc((size_t)8 * 2046 * 1024 * 2);
  bf16*  ws13 = (bf16*) alloc((size_t)2046 * 1024 * 2);
  bf16*  w2b  = (bf16*) alloc((size_t)8 * 1023 * 1024 * 2);
  bf16*  ws2b = (bf16*) alloc((size_t)1023 * 1024 * 2);

  float* ss_r  = ss;
  float* ss_z  = ss + TOK;
  float* ss_or = ss + 2 * TOK;
  float* ss_oz = ss + 3 * TOK;

  convert_kernel<<<NCVT, 128, 0, stream>>>(W1, W3, W2, Ws1, Ws3, Ws2,
                                           w13, ws13, w2b, ws2b);
  gate_cvt_kernel<<<TOK, 256, 0, stream>>>(x, gate_w, gate_b, x_bf, eidx, ewgt, ss);
  route_kernel<<<1, 256, 0, stream>>>(eidx, perm, posf, wl1, wn, wl2, wn + 1);
  mlp1_kernel<<<S1MAX * 16, 256, 0, stream>>>(x_bf, w13, ws13, perm, wl1, wn,
                                              h_r, h_s, ss_r, ss_z);
  finalize_t_kernel<<<8, 256, 0, stream>>>(ss_r, ss_z, h_r, h_s);
  mlp2_kernel<<<S2MAX * 8, 256, 0, stream>>>(h_r, h_s, w2b, ws2b, wl2, wn + 1,
                                             o_r, o_s, ss_or, ss_oz);
  combine_kernel<<<TOK, 256, 0, stream>>>(o_r, o_s, ss_or, ss_oz, posf, ewgt, out);
}